// Round 5
// baseline (441.060 us; speedup 1.0000x reference)
//
#include <hip/hip_runtime.h>
#include <hip/hip_bf16.h>

using bf16 = __hip_bfloat16;

using frag_ab = __attribute__((ext_vector_type(8))) short;  // 8 bf16 = 4 VGPRs
using frag_cd = __attribute__((ext_vector_type(4))) float;  // 4 fp32 acc

#define TM 128
#define TN 128
#define TK 32

__device__ __forceinline__ unsigned short f2bu(float f) {
    bf16 h = __float2bfloat16(f);
    return *(unsigned short*)&h;
}

__device__ __forceinline__ void st_c(float* p, float v) { *p = v; }
__device__ __forceinline__ void st_c(bf16* p, float v)  { *p = __float2bfloat16(v); }

// 16B-per-lane async global->LDS. Per-wave LDS dest = uniform base + lane*16 (required).
__device__ __forceinline__ void load16(const bf16* g, bf16* l) {
    __builtin_amdgcn_global_load_lds(
        (const __attribute__((address_space(1))) unsigned int*)g,
        (__attribute__((address_space(3))) unsigned int*)l,
        16, 0, 0);
}

// s_waitcnt vmcnt(4), lgkmcnt/expcnt untouched: imm = 4 | (7<<4) | (15<<8) = 0xF74
#define WAIT_VM4()  __builtin_amdgcn_s_waitcnt(0x0F74)
#define FENCE()     __asm__ __volatile__("" ::: "memory")

// C[m][n] = scale * sum_k A[m][k]*B[n][k] (+ bias[n]) (+ -inf where mask[n]!=0).
// A: M x K rows k-contig stride lda; B: N x K rows k-contig stride ldb.
// 128x128 tile, BK=32, 4 waves 2x2, each wave 64x64 via 4x4 MFMA 16x16x32.
// TRIPLE-buffered LDS, prefetch distance 2, raw s_barrier + manual vmcnt(4):
// the barrier waits only the stage about to be consumed; the next stage stays
// in flight across the barrier (~2 compute phases of latency budget).
// Bank swizzle: LDS slot (row, chunk c) holds global chunk (c-(row>>1))&3;
// reader uses chunk (quad+(lrow>>1))&3  -> 0 LDS bank conflicts (verified r4).
template <typename TC, bool HAS_BIAS, bool MASK>
__global__ __launch_bounds__(256, 4)
void mfma_gemm_nt(const bf16* __restrict__ A, const bf16* __restrict__ B,
                  const float* __restrict__ bias, const int* __restrict__ mask,
                  TC* __restrict__ C, int N, int K, int lda, int ldb, int ldc,
                  long sA, long sB, long sC, long sM, float scale)
{
    __shared__ bf16 As[3][TM][TK];   // 3 x 8 KB
    __shared__ bf16 Bs[3][TN][TK];   // 3 x 8 KB  (48 KB total -> 3 blocks/CU)

    const int bz = blockIdx.z;
    const bf16* Ab = A + (long)bz * sA;
    const bf16* Bb = B + (long)bz * sB;
    TC* Cb = C + (long)bz * sC;
    const int* maskb = MASK ? (mask + (long)bz * sM) : nullptr;

    const int t  = threadIdx.x;
    const int m0 = blockIdx.x * TM;
    const int n0 = blockIdx.y * TN;

    // staging: thread t fills LDS slot (srow, chunk c); fetches swizzled global chunk
    const int srow = t >> 2;                           // 0..63
    const int c    = t & 3;                            // 16B chunk in LDS row
    const int gco  = (((c - (srow >> 1)) & 3) << 3);   // swizzled global k offset
    const int lco  = c << 3;                           // LDS elem offset (linear)
    const bf16* ga0 = Ab + (long)(m0 + srow) * lda + gco;
    const bf16* ga1 = ga0 + (long)64 * lda;            // +64 rows: same swizzle mod 4
    const bf16* gb0 = Bb + (long)(n0 + srow) * ldb + gco;
    const bf16* gb1 = gb0 + (long)64 * ldb;

    const int wave = t >> 6;
    const int lane = t & 63;
    const int wm   = (wave & 1) * 64;
    const int wn   = (wave >> 1) * 64;
    const int lrow = lane & 15;
    const int quad = lane >> 4;
    const int rco  = (((quad + (lrow >> 1)) & 3) << 3);  // reader-side swizzle

    frag_cd acc[4][4] = {};

#define STAGE(buf)                                         \
    do {                                                   \
        load16(ga0, &As[buf][srow][lco]);                  \
        load16(ga1, &As[buf][srow + 64][lco]);             \
        load16(gb0, &Bs[buf][srow][lco]);                  \
        load16(gb1, &Bs[buf][srow + 64][lco]);             \
        ga0 += TK; ga1 += TK; gb0 += TK; gb1 += TK;        \
    } while (0)

    const int nIt = K / TK;
    STAGE(0);
    STAGE(1);                  // 8 loads outstanding

    int cur = 0, nxt = 2;
    for (int it = 0; it < nIt; ++it) {
        // wait only the 4 oldest loads (stage 'cur'); stage 'cur+1' stays in flight
        WAIT_VM4();
        FENCE();
        __builtin_amdgcn_s_barrier();
        FENCE();

        if (it + 2 < nIt) {
            STAGE(nxt);        // distance-2 prefetch, ~2 compute phases in flight
            nxt = (nxt == 2) ? 0 : nxt + 1;
        }

        frag_ab af[4], bfv[4];
#pragma unroll
        for (int i = 0; i < 4; ++i)
            af[i] = *(const frag_ab*)&As[cur][wm + i * 16 + lrow][rco];
#pragma unroll
        for (int j = 0; j < 4; ++j)
            bfv[j] = *(const frag_ab*)&Bs[cur][wn + j * 16 + lrow][rco];
#pragma unroll
        for (int i = 0; i < 4; ++i)
#pragma unroll
            for (int j = 0; j < 4; ++j)
                acc[i][j] = __builtin_amdgcn_mfma_f32_16x16x32_bf16(
                    af[i], bfv[j], acc[i][j], 0, 0, 0);

        cur = (cur == 2) ? 0 : cur + 1;
    }
#undef STAGE

    // epilogue: C/D layout col=lane&15, row=quad*4+reg  [m89-verified]
#pragma unroll
    for (int j = 0; j < 4; ++j) {
        const int col = n0 + wn + j * 16 + lrow;
        const float bv = HAS_BIAS ? bias[col] : 0.0f;
        const bool msk = MASK ? (maskb[col] != 0) : false;
#pragma unroll
        for (int i = 0; i < 4; ++i) {
            const int rbase = m0 + wm + i * 16 + quad * 4;
#pragma unroll
            for (int r = 0; r < 4; ++r) {
                float v = acc[i][j][r] * scale + bv;
                if (MASK && msk) v = -INFINITY;
                st_c(&Cb[(long)(rbase + r) * ldc + col], v);
            }
        }
    }
}

// fp32 X[b][s][h] -> bf16 Xb[b][s][h] and bf16 XT[b][h][s], 64x64 tiles.
__global__ __launch_bounds__(256)
void convert_transpose(const float* __restrict__ X, bf16* __restrict__ Xb,
                       bf16* __restrict__ XT, int S, int H)
{
    __shared__ unsigned short tile[64][72];
    const int b = blockIdx.z;
    const float* Xp = X + (long)b * S * H;
    bf16* Xbp = Xb + (long)b * S * H;
    bf16* XTp = XT + (long)b * H * S;
    const int h0 = blockIdx.x * 64, s0 = blockIdx.y * 64;
    const int t = threadIdx.x;
    const int r  = t >> 4;
    const int c4 = (t & 15) * 4;

#pragma unroll
    for (int p = 0; p < 4; ++p) {
        const int row = r + p * 16;
        const float4 v = *(const float4*)&Xp[(long)(s0 + row) * H + h0 + c4];
        ushort4 u;
        u.x = f2bu(v.x); u.y = f2bu(v.y); u.z = f2bu(v.z); u.w = f2bu(v.w);
        *(ushort4*)&tile[row][c4] = u;
        *(ushort4*)&Xbp[(long)(s0 + row) * H + h0 + c4] = u;
    }
    __syncthreads();
#pragma unroll
    for (int p = 0; p < 4; ++p) {
        const int hrow = r + p * 16;
        ushort4 u;
        u.x = tile[c4 + 0][hrow];
        u.y = tile[c4 + 1][hrow];
        u.z = tile[c4 + 2][hrow];
        u.w = tile[c4 + 3][hrow];
        *(ushort4*)&XTp[(long)(h0 + hrow) * S + s0 + c4] = u;
    }
}

// weights -> bf16 stacked [2*H*H]; final block packs bias [bq;bk].
__global__ __launch_bounds__(256)
void convert_w2(const float* __restrict__ wa, const float* __restrict__ wb,
                bf16* __restrict__ out, int n4each,
                const float* __restrict__ qb, const float* __restrict__ kb,
                float* __restrict__ biasP, int H)
{
    const int blk = blockIdx.x;
    if (blk == 2 * n4each / 256) {   // last block: pack bias (2H floats)
        for (int i = threadIdx.x; i < 2 * H; i += 256)
            biasP[i] = (i < H) ? qb[i] : kb[i - H];
        return;
    }
    const int i = blk * 256 + threadIdx.x;
    const bool second = i >= n4each;
    const float* src = second ? wb : wa;
    const int j = second ? i - n4each : i;
    const float4 v = ((const float4*)src)[j];
    ushort4 u;
    u.x = f2bu(v.x); u.y = f2bu(v.y); u.z = f2bu(v.z); u.w = f2bu(v.w);
    ((ushort4*)out)[i] = u;
}

// In-place softmax over rows (Slen=2048 bf16). Mask pre-applied as -inf.
__global__ __launch_bounds__(256)
void softmax_kernel(bf16* __restrict__ Smat, int Slen)
{
    const int row = blockIdx.x;
    bf16* srow = Smat + (long)row * Slen;

    const int t    = threadIdx.x;
    const int lane = t & 63;
    const int wid  = t >> 6;

    ushort4 u0 = ((const ushort4*)srow)[t * 2];
    ushort4 u1 = ((const ushort4*)srow)[t * 2 + 1];

    float vals[8];
    {
        const unsigned short us[8] = {u0.x, u0.y, u0.z, u0.w, u1.x, u1.y, u1.z, u1.w};
#pragma unroll
        for (int i = 0; i < 8; ++i) {
            unsigned int w = (unsigned int)us[i] << 16;
            vals[i] = *(float*)&w;
        }
    }

    float mx = vals[0];
#pragma unroll
    for (int i = 1; i < 8; ++i) mx = fmaxf(mx, vals[i]);

    __shared__ float red[4];
#pragma unroll
    for (int o = 32; o > 0; o >>= 1) mx = fmaxf(mx, __shfl_xor(mx, o, 64));
    if (lane == 0) red[wid] = mx;
    __syncthreads();
    mx = fmaxf(fmaxf(red[0], red[1]), fmaxf(red[2], red[3]));
    __syncthreads();

    float sum = 0.0f;
#pragma unroll
    for (int i = 0; i < 8; ++i) {
        const float e = __expf(vals[i] - mx);   // exp(-inf - mx) = 0
        vals[i] = e;
        sum += e;
    }
#pragma unroll
    for (int o = 32; o > 0; o >>= 1) sum += __shfl_xor(sum, o, 64);
    if (lane == 0) red[wid] = sum;
    __syncthreads();
    sum = red[0] + red[1] + red[2] + red[3];

    const float inv = 1.0f / sum;
    ushort4 o0, o1;
    o0.x = f2bu(vals[0] * inv); o0.y = f2bu(vals[1] * inv);
    o0.z = f2bu(vals[2] * inv); o0.w = f2bu(vals[3] * inv);
    o1.x = f2bu(vals[4] * inv); o1.y = f2bu(vals[5] * inv);
    o1.z = f2bu(vals[6] * inv); o1.w = f2bu(vals[7] * inv);
    ((ushort4*)srow)[t * 2]     = o0;
    ((ushort4*)srow)[t * 2 + 1] = o1;
}

extern "C" void kernel_launch(void* const* d_in, const int* in_sizes, int n_in,
                              void* d_out, int out_size, void* d_ws, size_t ws_size,
                              hipStream_t stream)
{
    const float* hidden = (const float*)d_in[0];
    const int*   mask   = (const int*)d_in[1];
    const float* Wq_w   = (const float*)d_in[2];
    const float* Wq_b   = (const float*)d_in[3];
    const float* Wk_w   = (const float*)d_in[4];
    const float* Wk_b   = (const float*)d_in[5];
    float* out = (float*)d_out;

    const int B = 8, S = 2048, H = 1024;
    const int M = B * S;               // 16384
    const long MH = (long)M * H;       // 16.7M elems

    // ws (bf16 elems): QK[M][2H] (67MB) | XbT (33.5MB) | Sb (67MB)
    // Xb + Wb (stacked weights) + packed bias aliased inside Sb (dead before scores).
    bf16* QK  = (bf16*)d_ws;
    bf16* XbT = QK + MH * 2;
    bf16* Sb  = XbT + MH;
    bf16* Xb  = Sb;                    // aliased
    bf16* Wb  = Xb + MH;               // [2H][H] = Wq stacked on Wk
    float* biasP = (float*)(Wb + 2L * H * H);  // 2048 floats

    const dim3 blk(256);

    convert_transpose<<<dim3(H / 64, S / 64, B), blk, 0, stream>>>(hidden, Xb, XbT, S, H);
    convert_w2<<<dim3(2 * H * H / 1024 + 1), blk, 0, stream>>>(
        Wq_w, Wk_w, Wb, H * H / 4, Wq_b, Wk_b, biasP, H);

    // QK = Xb @ [Wq;Wk]^T + [bq;bk]   (merged, N = 2H)
    mfma_gemm_nt<bf16, true, false><<<dim3(M / TM, 2 * H / TN, 1), blk, 0, stream>>>(
        Xb, Wb, biasP, nullptr, QK, 2 * H, H, H, H, 2 * H, 0, 0, 0, 0, 1.0f);

    // Scores_b = (Q_b @ K_b^T)/32, mask applied as -inf in epilogue
    mfma_gemm_nt<bf16, false, true><<<dim3(S / TM, S / TN, B), blk, 0, stream>>>(
        QK, QK + H, nullptr, mask, Sb, S, H, 2 * H, 2 * H, S,
        (long)S * 2 * H, (long)S * 2 * H, (long)S * S, S, 1.0f / 32.0f);

    // softmax in place (mask already -inf)
    softmax_kernel<<<dim3(B * S), blk, 0, stream>>>(Sb, S);

    // Out_b = P_b @ X_b  (B operand = XbT, k-contig)
    mfma_gemm_nt<float, false, false><<<dim3(S / TM, H / TN, B), blk, 0, stream>>>(
        Sb, XbT, nullptr, nullptr, out, H, S, S, S, H,
        (long)S * S, (long)H * S, (long)S * H, 0, 1.0f);
}